// Round 7
// baseline (643.350 us; speedup 1.0000x reference)
//
#include <hip/hip_runtime.h>
#include <hip/hip_fp16.h>

// SparseConvTransposeBlock, round 15: slot-binned REGISTER accumulation.
//
// R14 ledger: merge loop (~240us) and b_reorder (~150us) are the costs.
// Fix: bin entries into ROW-INDEXED slots (entry for row rl at position rl
// of layer s) so MFMA A-row position == rl. C-tile rows then align with a
// per-wave register accumulator held across all k and layers: NO merge, NO
// barriers, NO LDS image. Slot assignment via byte-packed atomic counters
// (4 rl counts/word). Duplicates beyond SLOTS=2 per (k,rl) (~30/bucket) go
// to a per-bucket overflow list, processed in-kernel by masked 1-row MFMAs.
// BN stats fused into the epilogue (k2 eliminated). fp32 reg accumulation.
//
// Fallbacks: R6 fp16-atomic path, then R1 fp32 path.

#define C_DIM 64
#define LDS_STRIDE 72   // bf16 elems per Wt row: 64 + 8 pad
#define ROW_STRIDE 68   // fp32 elems per scratch row: 64 + 4 pad

#define BUCKET_BITS 7                 // 128 output rows per bucket
#define BUCKET_ROWS (1 << BUCKET_BITS)
#define SLOTS 2                       // slot layers per (k,rl)
#define OVF_CAP 256                   // per-bucket overflow capacity

typedef __bf16 bf16_t;
typedef bf16_t bf16x4 __attribute__((ext_vector_type(4)));
typedef bf16_t bf16x8 __attribute__((ext_vector_type(8)));
typedef float floatx4 __attribute__((ext_vector_type(4)));

// ---------------------------------------------- features f32 -> bf16 table
__global__ __launch_bounds__(256)
void k_fprep(const float* __restrict__ f, bf16_t* __restrict__ fb, int total4)
{
    int i = blockIdx.x * 256 + threadIdx.x;
    if (i < total4) {
        float4 v = ((const float4*)f)[i];
        bf16x4 o;
        o[0] = (bf16_t)v.x; o[1] = (bf16_t)v.y;
        o[2] = (bf16_t)v.z; o[3] = (bf16_t)v.w;
        ((bf16x4*)fb)[i] = o;
    }
}

// ------------- W -> per-lane MFMA B-fragment layout (bf16), 128B per lane.
// wp[k][lane][(ks*4+nt)*8 + j] = W[k][quad*8+j+32*ks][col+16*nt]   (proven R9+)
__global__ __launch_bounds__(64)
void w_prep(const float* __restrict__ w, bf16_t* __restrict__ wp)
{
    int k = blockIdx.x;
    int lane = threadIdx.x;
    int quad = lane >> 4, col = lane & 15;
    const float* Wk = w + (size_t)k * C_DIM * C_DIM;
    bf16_t* dst = wp + ((size_t)(k * 64 + lane)) * 64;
    #pragma unroll
    for (int ks = 0; ks < 2; ++ks)
        #pragma unroll
        for (int nt = 0; nt < 4; ++nt)
            #pragma unroll
            for (int j = 0; j < 8; ++j)
                dst[(ks * 4 + nt) * 8 + j] =
                    (bf16_t)Wk[(quad * 8 + j + 32 * ks) * C_DIM + col + 16 * nt];
}

// ------------- slot binning: per (k, bucket, rl) byte-packed atomic count;
// entry 'in' stored at entries2[(bin*SLOTS+pos)*128 + rl]; overflow (pos>=S)
// appended to per-bucket list as k[28:24]|rl[23:17]|in[16:0].
__global__ __launch_bounds__(256)
void b_reorder2(const int* __restrict__ pin, const int* __restrict__ pout,
                unsigned* __restrict__ slotpk, unsigned* __restrict__ entries2,
                int* __restrict__ ovfcnt, unsigned* __restrict__ ovf,
                int P, int NB)
{
    int k = blockIdx.y;
    int i = blockIdx.x * 256 + threadIdx.x;
    if (i >= P) return;
    int o  = pout[(size_t)k * P + i];
    int in = pin [(size_t)k * P + i];
    int rl     = o & (BUCKET_ROWS - 1);
    int bucket = o >> BUCKET_BITS;
    size_t bin = (size_t)k * NB + bucket;
    unsigned shift = 8u * (unsigned)(rl & 3);
    unsigned old = atomicAdd(&slotpk[(bin << 5) + (rl >> 2)], 1u << shift);
    unsigned pos = (old >> shift) & 255u;
    if (pos < SLOTS) {
        entries2[((bin * SLOTS + pos) << BUCKET_BITS) + rl] = (unsigned)in;
    } else {
        int op = atomicAdd(&ovfcnt[bucket], 1);
        if (op < OVF_CAP)
            ovf[((size_t)bucket << 8) + op] =
                ((unsigned)k << 24) | ((unsigned)rl << 17) | (unsigned)in;
    }
}

// ------------- main: block b owns bucket b; wave w owns rows [32w,32w+32).
// Registers accumulate across all k and slot layers; no barriers, no merge.
__global__ __launch_bounds__(256)
void k_bucket_reg(const bf16_t* __restrict__ fb, const bf16_t* __restrict__ wp,
                  const unsigned* __restrict__ slotpk,
                  const unsigned* __restrict__ entries2,
                  const int* __restrict__ ovfcnt, const unsigned* __restrict__ ovf,
                  float* __restrict__ out, float* __restrict__ sums,
                  int NB, int n_out, int K3)
{
    const int tid  = threadIdx.x;
    const int wave = tid >> 6;
    const int lane = tid & 63;
    const int quad = lane >> 4;
    const int col  = lane & 15;
    const int b    = blockIdx.x;
    const int row0 = b << BUCKET_BITS;

    bf16x8 zer;
    #pragma unroll
    for (int j = 0; j < 8; ++j) zer[j] = (bf16_t)0.f;

    floatx4 acc0[4], acc1[4];           // st=0 rows 32w+[0,16), st=1 +[16,32)
    #pragma unroll
    for (int nt = 0; nt < 4; ++nt) {
        acc0[nt] = (floatx4){0.f, 0.f, 0.f, 0.f};
        acc1[nt] = (floatx4){0.f, 0.f, 0.f, 0.f};
    }

    const int rl0 = wave * 32 + col;    // lane's A-row for st=0
    const int rl1 = rl0 + 16;           // st=1

    for (int k = 0; k < K3; ++k) {
        size_t bin = (size_t)k * NB + b;

        const bf16_t* wpk = wp + ((size_t)(k * 64 + lane)) * 64;
        bf16x8 bf[2][4];
        #pragma unroll
        for (int ks = 0; ks < 2; ++ks)
            #pragma unroll
            for (int nt = 0; nt < 4; ++nt)
                bf[ks][nt] = *(const bf16x8*)(wpk + (ks * 4 + nt) * 8);

        unsigned pw0 = slotpk[(bin << 5) + (rl0 >> 2)];
        unsigned pw1 = slotpk[(bin << 5) + (rl1 >> 2)];
        int c0 = (int)((pw0 >> (8 * (rl0 & 3))) & 255u);
        int c1 = (int)((pw1 >> (8 * (rl1 & 3))) & 255u);

        const unsigned* e2 = entries2 + ((size_t)(bin * SLOTS) << BUCKET_BITS);
        #pragma unroll
        for (int s = 0; s < SLOTS; ++s) {
            bool v0 = (s < c0);
            if (__any(v0)) {
                bf16x8 a0 = zer, a1 = zer;
                if (v0) {
                    unsigned in = e2[(s << BUCKET_BITS) + rl0] & 0x1FFFFu;
                    const bf16_t* src = fb + ((size_t)in << 6) + quad * 8;
                    a0 = *(const bf16x8*)(src);
                    a1 = *(const bf16x8*)(src + 32);
                }
                #pragma unroll
                for (int nt = 0; nt < 4; ++nt) {
                    acc0[nt] = __builtin_amdgcn_mfma_f32_16x16x32_bf16(a0, bf[0][nt], acc0[nt], 0, 0, 0);
                    acc0[nt] = __builtin_amdgcn_mfma_f32_16x16x32_bf16(a1, bf[1][nt], acc0[nt], 0, 0, 0);
                }
            }
            bool v1 = (s < c1);
            if (__any(v1)) {
                bf16x8 a0 = zer, a1 = zer;
                if (v1) {
                    unsigned in = e2[(s << BUCKET_BITS) + rl1] & 0x1FFFFu;
                    const bf16_t* src = fb + ((size_t)in << 6) + quad * 8;
                    a0 = *(const bf16x8*)(src);
                    a1 = *(const bf16x8*)(src + 32);
                }
                #pragma unroll
                for (int nt = 0; nt < 4; ++nt) {
                    acc1[nt] = __builtin_amdgcn_mfma_f32_16x16x32_bf16(a0, bf[0][nt], acc1[nt], 0, 0, 0);
                    acc1[nt] = __builtin_amdgcn_mfma_f32_16x16x32_bf16(a1, bf[1][nt], acc1[nt], 0, 0, 0);
                }
            }
        }
    }

    // ---- overflow entries (rare, ~30/bucket): masked single-row MFMA ----
    int nov = min(ovfcnt[b], OVF_CAP);
    for (int i = 0; i < nov; ++i) {
        unsigned wd = ovf[((size_t)b << 8) + i];
        int rl = (int)((wd >> 17) & 127u);
        if ((rl >> 5) != wave) continue;          // owning wave only
        int ko = (int)(wd >> 24);
        int in = (int)(wd & 0x1FFFFu);
        const bf16_t* wpk = wp + ((size_t)(ko * 64 + lane)) * 64;
        bf16x8 bo[2][4];
        #pragma unroll
        for (int ks = 0; ks < 2; ++ks)
            #pragma unroll
            for (int nt = 0; nt < 4; ++nt)
                bo[ks][nt] = *(const bf16x8*)(wpk + (ks * 4 + nt) * 8);
        bf16x8 a0 = zer, a1 = zer;
        if (col == (rl & 15)) {
            const bf16_t* src = fb + ((size_t)in << 6) + quad * 8;
            a0 = *(const bf16x8*)(src);
            a1 = *(const bf16x8*)(src + 32);
        }
        if (((rl >> 4) & 1) == 0) {
            #pragma unroll
            for (int nt = 0; nt < 4; ++nt) {
                acc0[nt] = __builtin_amdgcn_mfma_f32_16x16x32_bf16(a0, bo[0][nt], acc0[nt], 0, 0, 0);
                acc0[nt] = __builtin_amdgcn_mfma_f32_16x16x32_bf16(a1, bo[1][nt], acc0[nt], 0, 0, 0);
            }
        } else {
            #pragma unroll
            for (int nt = 0; nt < 4; ++nt) {
                acc1[nt] = __builtin_amdgcn_mfma_f32_16x16x32_bf16(a0, bo[0][nt], acc1[nt], 0, 0, 0);
                acc1[nt] = __builtin_amdgcn_mfma_f32_16x16x32_bf16(a1, bo[1][nt], acc1[nt], 0, 0, 0);
            }
        }
    }

    // ---- epilogue: linear fp32 writeout + fused BN partial stats ----
    // C layout: row = 32*wave + 16*st + quad*4 + r, ch = col + 16*nt.
    float s_nt[4], q_nt[4];
    #pragma unroll
    for (int nt = 0; nt < 4; ++nt) { s_nt[nt] = 0.f; q_nt[nt] = 0.f; }

    #pragma unroll
    for (int nt = 0; nt < 4; ++nt) {
        #pragma unroll
        for (int r = 0; r < 4; ++r) {
            int gr0 = row0 + wave * 32 + quad * 4 + r;
            float v0 = acc0[nt][r];
            s_nt[nt] += v0; q_nt[nt] += v0 * v0;
            if (gr0 < n_out)
                out[((size_t)gr0 << 6) + col + 16 * nt] = v0;
            int gr1 = gr0 + 16;
            float v1 = acc1[nt][r];
            s_nt[nt] += v1; q_nt[nt] += v1 * v1;
            if (gr1 < n_out)
                out[((size_t)gr1 << 6) + col + 16 * nt] = v1;
        }
    }

    __shared__ float red_s[4][64];
    __shared__ float red_q[4][64];
    #pragma unroll
    for (int nt = 0; nt < 4; ++nt) {      // reduce across the 4 quads
        s_nt[nt] += __shfl_xor(s_nt[nt], 16);
        s_nt[nt] += __shfl_xor(s_nt[nt], 32);
        q_nt[nt] += __shfl_xor(q_nt[nt], 16);
        q_nt[nt] += __shfl_xor(q_nt[nt], 32);
    }
    if (quad == 0) {
        #pragma unroll
        for (int nt = 0; nt < 4; ++nt) {
            red_s[wave][col + 16 * nt] = s_nt[nt];
            red_q[wave][col + 16 * nt] = q_nt[nt];
        }
    }
    __syncthreads();
    if (tid < 64) {
        float ts = red_s[0][tid] + red_s[1][tid] + red_s[2][tid] + red_s[3][tid];
        float tq = red_q[0][tid] + red_q[1][tid] + red_q[2][tid] + red_q[3][tid];
        unsafeAtomicAdd(&sums[tid], ts);
        unsafeAtomicAdd(&sums[64 + tid], tq);
    }
}

// ------------------------- BN normalize + ReLU: fp32 in-place (proven R1)
__global__ __launch_bounds__(256)
void k3_bn_relu(float* __restrict__ out, const float* __restrict__ sums,
                const float* __restrict__ gamma, const float* __restrict__ beta,
                int n_rows)
{
    int tid = blockIdx.x * 256 + threadIdx.x;
    int ch0 = (tid * 4) & 63;
    float inv_n = 1.0f / (float)n_rows;
    float sc[4], sh[4];
    #pragma unroll
    for (int j = 0; j < 4; ++j) {
        int ch    = ch0 + j;
        float m   = sums[ch] * inv_n;
        float var = sums[64 + ch] * inv_n - m * m;
        float inv = rsqrtf(var + 1e-5f);
        float g   = gamma[ch] * inv;
        sc[j] = g;
        sh[j] = beta[ch] - m * g;
    }
    size_t total = (size_t)n_rows * C_DIM / 4;
    for (size_t i = tid; i < total; i += (size_t)gridDim.x * 256) {
        float4 v = ((const float4*)out)[i];
        v.x = fmaxf(v.x * sc[0] + sh[0], 0.f);
        v.y = fmaxf(v.y * sc[1] + sh[1], 0.f);
        v.z = fmaxf(v.z * sc[2] + sh[2], 0.f);
        v.w = fmaxf(v.w * sc[3] + sh[3], 0.f);
        ((float4*)out)[i] = v;
    }
}

// ======================= R6 main kernel (proven fallback) ===================
__global__ __launch_bounds__(256)
void k1_fp16(const float* __restrict__ features,
             const bf16_t* __restrict__ fbf16,
             const float* __restrict__ weight,
             const int* __restrict__ pairs_in,
             const int* __restrict__ pairs_out,
             __half* __restrict__ acc,
             int P, int rows_per_block, int use_bf16)
{
    __shared__ bf16_t Wt[C_DIM * LDS_STRIDE];
    __shared__ float  scratch[4][16 * ROW_STRIDE];

    const int k   = blockIdx.y;
    const int tid = threadIdx.x;

    const float* Wk = weight + (size_t)k * C_DIM * C_DIM;
    for (int i = tid; i < C_DIM * C_DIM; i += 256) {
        int c = i >> 6, d = i & 63;
        Wt[d * LDS_STRIDE + c] = (bf16_t)Wk[i];
    }
    __syncthreads();

    const int wave = tid >> 6;
    const int lane = tid & 63;
    const int quad = lane >> 4;
    const int col  = lane & 15;
    const int sub  = lane >> 5;
    const int c2   = lane & 31;
    float* ls = &scratch[wave][0];

    bf16x8 bfrag[2][4];
    #pragma unroll
    for (int ks = 0; ks < 2; ++ks)
        #pragma unroll
        for (int nt = 0; nt < 4; ++nt)
            bfrag[ks][nt] =
                *(const bf16x8*)&Wt[(col + 16 * nt) * LDS_STRIDE + quad * 8 + 32 * ks];

    const int* __restrict__ pin  = pairs_in  + (size_t)k * P;
    const int* __restrict__ pout = pairs_out + (size_t)k * P;

    const int p0   = blockIdx.x * rows_per_block;
    const int pend = min(p0 + rows_per_block, P);

    for (int base = p0 + wave * 16; base < pend; base += 64) {
        int prow    = base + col;
        int clamped = (prow < pend) ? prow : (pend - 1);
        int in_idx  = pin[clamped];
        int out_idx = pout[clamped];

        bf16x8 a0, a1;
        if (use_bf16) {
            const bf16_t* src = fbf16 + (size_t)in_idx * C_DIM + quad * 8;
            a0 = *(const bf16x8*)(src);
            a1 = *(const bf16x8*)(src + 32);
        } else {
            const float* src = features + (size_t)in_idx * C_DIM + quad * 8;
            float4 f0 = *(const float4*)(src);
            float4 f1 = *(const float4*)(src + 4);
            float4 f2 = *(const float4*)(src + 32);
            float4 f3 = *(const float4*)(src + 36);
            a0[0] = (bf16_t)f0.x; a0[1] = (bf16_t)f0.y; a0[2] = (bf16_t)f0.z; a0[3] = (bf16_t)f0.w;
            a0[4] = (bf16_t)f1.x; a0[5] = (bf16_t)f1.y; a0[6] = (bf16_t)f1.z; a0[7] = (bf16_t)f1.w;
            a1[0] = (bf16_t)f2.x; a1[1] = (bf16_t)f2.y; a1[2] = (bf16_t)f2.z; a1[3] = (bf16_t)f2.w;
            a1[4] = (bf16_t)f3.x; a1[5] = (bf16_t)f3.y; a1[6] = (bf16_t)f3.z; a1[7] = (bf16_t)f3.w;
        }

        floatx4 acc0 = {0.f, 0.f, 0.f, 0.f};
        floatx4 acc1 = {0.f, 0.f, 0.f, 0.f};
        floatx4 acc2 = {0.f, 0.f, 0.f, 0.f};
        floatx4 acc3 = {0.f, 0.f, 0.f, 0.f};

        acc0 = __builtin_amdgcn_mfma_f32_16x16x32_bf16(a0, bfrag[0][0], acc0, 0, 0, 0);
        acc0 = __builtin_amdgcn_mfma_f32_16x16x32_bf16(a1, bfrag[1][0], acc0, 0, 0, 0);
        acc1 = __builtin_amdgcn_mfma_f32_16x16x32_bf16(a0, bfrag[0][1], acc1, 0, 0, 0);
        acc1 = __builtin_amdgcn_mfma_f32_16x16x32_bf16(a1, bfrag[1][1], acc1, 0, 0, 0);
        acc2 = __builtin_amdgcn_mfma_f32_16x16x32_bf16(a0, bfrag[0][2], acc2, 0, 0, 0);
        acc2 = __builtin_amdgcn_mfma_f32_16x16x32_bf16(a1, bfrag[1][2], acc2, 0, 0, 0);
        acc3 = __builtin_amdgcn_mfma_f32_16x16x32_bf16(a0, bfrag[0][3], acc3, 0, 0, 0);
        acc3 = __builtin_amdgcn_mfma_f32_16x16x32_bf16(a1, bfrag[1][3], acc3, 0, 0, 0);

        #pragma unroll
        for (int r = 0; r < 4; ++r) {
            int m = quad * 4 + r;
            ls[m * ROW_STRIDE + col +  0] = acc0[r];
            ls[m * ROW_STRIDE + col + 16] = acc1[r];
            ls[m * ROW_STRIDE + col + 32] = acc2[r];
            ls[m * ROW_STRIDE + col + 48] = acc3[r];
        }
        asm volatile("s_waitcnt lgkmcnt(0)" ::: "memory");

        #pragma unroll
        for (int m2 = 0; m2 < 8; ++m2) {
            int m = m2 * 2 + sub;
            float2 v = *(const float2*)&ls[m * ROW_STRIDE + 2 * c2];
            __half2 h = __floats2half2_rn(v.x, v.y);
            int g = __shfl(out_idx, m);
            if (base + m < pend)
                unsafeAtomicAdd((__half2*)(acc + (size_t)g * C_DIM + 2 * c2), h);
        }
    }
}

__global__ __launch_bounds__(256)
void k2_stats_h(const __half* __restrict__ acc, float* __restrict__ sums,
                int n_rows)
{
    const int tid = threadIdx.x;
    const int c8  = tid & 7;
    const int sub = tid >> 3;

    float s[8] = {0,0,0,0,0,0,0,0}, q[8] = {0,0,0,0,0,0,0,0};
    for (int r = blockIdx.x * 32 + sub; r < n_rows; r += gridDim.x * 32) {
        float4 v = *(const float4*)&acc[(size_t)r * C_DIM + c8 * 8];
        const __half2* h = (const __half2*)&v;
        #pragma unroll
        for (int j = 0; j < 4; ++j) {
            float x = __half2float(h[j].x), y = __half2float(h[j].y);
            s[2*j]   += x; q[2*j]   += x * x;
            s[2*j+1] += y; q[2*j+1] += y * y;
        }
    }

    __shared__ float red[128];
    if (tid < 128) red[tid] = 0.f;
    __syncthreads();
    #pragma unroll
    for (int j = 0; j < 8; ++j) {
        atomicAdd(&red[c8 * 8 + j], s[j]);
        atomicAdd(&red[64 + c8 * 8 + j], q[j]);
    }
    __syncthreads();
    if (tid < 128) atomicAdd(&sums[tid], red[tid]);
}

__global__ __launch_bounds__(256)
void k3_bn_relu_h(const __half* __restrict__ acc, float* __restrict__ out,
                  const float* __restrict__ sums,
                  const float* __restrict__ gamma, const float* __restrict__ beta,
                  int n_rows)
{
    int tid = blockIdx.x * 256 + threadIdx.x;
    int c8  = tid & 7;
    float inv_n = 1.0f / (float)n_rows;

    float sc[8], sh[8];
    #pragma unroll
    for (int j = 0; j < 8; ++j) {
        int ch    = c8 * 8 + j;
        float m   = sums[ch] * inv_n;
        float var = sums[64 + ch] * inv_n - m * m;
        float inv = rsqrtf(var + 1e-5f);
        float g   = gamma[ch] * inv;
        sc[j] = g;
        sh[j] = beta[ch] - m * g;
    }

    size_t total = (size_t)n_rows * 8;
    for (size_t i = tid; i < total; i += (size_t)gridDim.x * 256) {
        float4 v = ((const float4*)acc)[i];
        const __half2* h = (const __half2*)&v;
        float4 o0, o1;
        o0.x = fmaxf(__half2float(h[0].x) * sc[0] + sh[0], 0.f);
        o0.y = fmaxf(__half2float(h[0].y) * sc[1] + sh[1], 0.f);
        o0.z = fmaxf(__half2float(h[1].x) * sc[2] + sh[2], 0.f);
        o0.w = fmaxf(__half2float(h[1].y) * sc[3] + sh[3], 0.f);
        o1.x = fmaxf(__half2float(h[2].x) * sc[4] + sh[4], 0.f);
        o1.y = fmaxf(__half2float(h[2].y) * sc[5] + sh[5], 0.f);
        o1.z = fmaxf(__half2float(h[3].x) * sc[6] + sh[6], 0.f);
        o1.w = fmaxf(__half2float(h[3].y) * sc[7] + sh[7], 0.f);
        ((float4*)out)[2 * i]     = o0;
        ((float4*)out)[2 * i + 1] = o1;
    }
}

// ===================== fallback (R1 path, proven) ===========================
__global__ __launch_bounds__(256)
void k1_scatter_gemm(const float* __restrict__ features,
                     const float* __restrict__ weight,
                     const int* __restrict__ pairs_in,
                     const int* __restrict__ pairs_out,
                     float* __restrict__ out,
                     int P, int rows_per_block)
{
    __shared__ bf16_t Wt[C_DIM * LDS_STRIDE];
    const int k   = blockIdx.y;
    const int tid = threadIdx.x;
    const float* Wk = weight + (size_t)k * C_DIM * C_DIM;
    for (int i = tid; i < C_DIM * C_DIM; i += 256) {
        int c = i >> 6, d = i & 63;
        Wt[d * LDS_STRIDE + c] = (bf16_t)Wk[i];
    }
    __syncthreads();
    const int wave = tid >> 6, lane = tid & 63, quad = lane >> 4, col = lane & 15;
    bf16x8 bfrag[2][4];
    #pragma unroll
    for (int ks = 0; ks < 2; ++ks)
        #pragma unroll
        for (int nt = 0; nt < 4; ++nt)
            bfrag[ks][nt] =
                *(const bf16x8*)&Wt[(col + 16 * nt) * LDS_STRIDE + quad * 8 + 32 * ks];
    const int* __restrict__ pin  = pairs_in  + (size_t)k * P;
    const int* __restrict__ pout = pairs_out + (size_t)k * P;
    const int p0   = blockIdx.x * rows_per_block;
    const int pend = min(p0 + rows_per_block, P);
    for (int base = p0 + wave * 16; base < pend; base += 64) {
        int prow    = base + col;
        int clamped = (prow < pend) ? prow : (pend - 1);
        int in_idx  = pin[clamped];
        int out_idx = pout[clamped];
        const float* src = features + (size_t)in_idx * C_DIM + quad * 8;
        float4 f0 = *(const float4*)(src);
        float4 f1 = *(const float4*)(src + 4);
        float4 f2 = *(const float4*)(src + 32);
        float4 f3 = *(const float4*)(src + 36);
        bf16x8 a0, a1;
        a0[0] = (bf16_t)f0.x; a0[1] = (bf16_t)f0.y; a0[2] = (bf16_t)f0.z; a0[3] = (bf16_t)f0.w;
        a0[4] = (bf16_t)f1.x; a0[5] = (bf16_t)f1.y; a0[6] = (bf16_t)f1.z; a0[7] = (bf16_t)f1.w;
        a1[0] = (bf16_t)f2.x; a1[1] = (bf16_t)f2.y; a1[2] = (bf16_t)f2.z; a1[3] = (bf16_t)f2.w;
        a1[4] = (bf16_t)f3.x; a1[5] = (bf16_t)f3.y; a1[6] = (bf16_t)f3.z; a1[7] = (bf16_t)f3.w;
        floatx4 acc0 = {0.f,0.f,0.f,0.f}, acc1 = {0.f,0.f,0.f,0.f};
        floatx4 acc2 = {0.f,0.f,0.f,0.f}, acc3 = {0.f,0.f,0.f,0.f};
        acc0 = __builtin_amdgcn_mfma_f32_16x16x32_bf16(a0, bfrag[0][0], acc0, 0, 0, 0);
        acc0 = __builtin_amdgcn_mfma_f32_16x16x32_bf16(a1, bfrag[1][0], acc0, 0, 0, 0);
        acc1 = __builtin_amdgcn_mfma_f32_16x16x32_bf16(a0, bfrag[0][1], acc1, 0, 0, 0);
        acc1 = __builtin_amdgcn_mfma_f32_16x16x32_bf16(a1, bfrag[1][1], acc1, 0, 0, 0);
        acc2 = __builtin_amdgcn_mfma_f32_16x16x32_bf16(a0, bfrag[0][2], acc2, 0, 0, 0);
        acc2 = __builtin_amdgcn_mfma_f32_16x16x32_bf16(a1, bfrag[1][2], acc2, 0, 0, 0);
        acc3 = __builtin_amdgcn_mfma_f32_16x16x32_bf16(a0, bfrag[0][3], acc3, 0, 0, 0);
        acc3 = __builtin_amdgcn_mfma_f32_16x16x32_bf16(a1, bfrag[1][3], acc3, 0, 0, 0);
        #pragma unroll
        for (int r = 0; r < 4; ++r) {
            int m = quad * 4 + r;
            int g = __shfl(out_idx, m);
            if (base + m < pend) {
                float* dst = out + (size_t)g * C_DIM + col;
                unsafeAtomicAdd(dst +  0, acc0[r]);
                unsafeAtomicAdd(dst + 16, acc1[r]);
                unsafeAtomicAdd(dst + 32, acc2[r]);
                unsafeAtomicAdd(dst + 48, acc3[r]);
            }
        }
    }
}

__global__ __launch_bounds__(256)
void k2_stats(const float* __restrict__ acc, float* __restrict__ sums, int n_rows)
{
    int tid = threadIdx.x;
    int ch  = tid & 63;
    int sub = tid >> 6;
    float s = 0.f, s2 = 0.f;
    for (int r = blockIdx.x * 4 + sub; r < n_rows; r += gridDim.x * 4) {
        float v = acc[(size_t)r * C_DIM + ch];
        s  += v;
        s2 += v * v;
    }
    __shared__ float red[256];
    red[tid] = s;
    __syncthreads();
    if (tid < 64) {
        float t = red[tid] + red[tid + 64] + red[tid + 128] + red[tid + 192];
        atomicAdd(&sums[ch], t);
    }
    __syncthreads();
    red[tid] = s2;
    __syncthreads();
    if (tid < 64) {
        float t = red[tid] + red[tid + 64] + red[tid + 128] + red[tid + 192];
        atomicAdd(&sums[64 + ch], t);
    }
}

// ============================================================================
extern "C" void kernel_launch(void* const* d_in, const int* in_sizes, int n_in,
                              void* d_out, int out_size, void* d_ws, size_t ws_size,
                              hipStream_t stream)
{
    const float* features  = (const float*)d_in[0];
    const float* weight    = (const float*)d_in[1];
    // d_in[2] = bias (cancels in training-mode BN)
    const float* gamma     = (const float*)d_in[3];
    const float* beta      = (const float*)d_in[4];
    const int*   pairs_in  = (const int*)d_in[5];
    const int*   pairs_out = (const int*)d_in[6];

    const int n_out     = out_size / C_DIM;
    const int n_in_rows = in_sizes[0] / C_DIM;
    const int K3        = in_sizes[1] / (C_DIM * C_DIM);
    const int P         = in_sizes[5] / K3;

    float* out = (float*)d_out;

    // -------- primary workspace: sums | ovfcnt | slotpk | entries2 | ovf | fb | wp
    const int    NB       = (n_out + BUCKET_ROWS - 1) >> BUCKET_BITS;
    const size_t NBINS    = (size_t)K3 * NB;
    const size_t off_ovfc = 512;
    const size_t off_slot = (off_ovfc + (size_t)NB * 4 + 255) & ~(size_t)255;
    const size_t slot_sz  = NBINS * BUCKET_ROWS;              // bytes (packed)
    const size_t off_e2   = (off_slot + slot_sz + 255) & ~(size_t)255;
    const size_t e2_sz    = NBINS * SLOTS * BUCKET_ROWS * 4;
    const size_t off_ovf  = (off_e2 + e2_sz + 255) & ~(size_t)255;
    const size_t ovf_sz   = (size_t)NB * OVF_CAP * 4;
    const size_t off_fb   = (off_ovf + ovf_sz + 255) & ~(size_t)255;
    const size_t fb_sz    = (size_t)n_in_rows * C_DIM * 2;
    const size_t off_wp   = (off_fb + fb_sz + 255) & ~(size_t)255;
    const size_t need_reg = off_wp + (size_t)K3 * C_DIM * C_DIM * 2;

    if (ws_size >= need_reg && n_in_rows <= (1 << 17) && K3 <= 31) {
        float*    sums   = (float*)d_ws;
        int*      ovfcnt = (int*)((char*)d_ws + off_ovfc);
        unsigned* slotpk = (unsigned*)((char*)d_ws + off_slot);
        unsigned* ent2   = (unsigned*)((char*)d_ws + off_e2);
        unsigned* ovf    = (unsigned*)((char*)d_ws + off_ovf);
        bf16_t*   fb     = (bf16_t*)((char*)d_ws + off_fb);
        bf16_t*   wpb    = (bf16_t*)((char*)d_ws + off_wp);

        // one clear: sums + ovfcnt + slotpk (contiguous prefix)
        hipMemsetAsync(d_ws, 0, off_slot + slot_sz, stream);
        k_fprep<<<(n_in_rows * 16 + 255) / 256, 256, 0, stream>>>(
            features, fb, n_in_rows * 16);
        w_prep<<<K3, 64, 0, stream>>>(weight, wpb);

        dim3 gr((P + 255) / 256, K3);
        b_reorder2<<<gr, 256, 0, stream>>>(pairs_in, pairs_out, slotpk, ent2,
                                           ovfcnt, ovf, P, NB);

        k_bucket_reg<<<NB, 256, 0, stream>>>(fb, wpb, slotpk, ent2, ovfcnt,
                                             ovf, out, sums, NB, n_out, K3);

        k3_bn_relu<<<dim3(1024), 256, 0, stream>>>(out, sums, gamma, beta, n_out);
        return;
    }

    // ---------------- R6 fp16-atomic path (proven fallback) ----------------
    size_t acc_bytes6 = (size_t)n_out * C_DIM * 2;
    size_t off_acc6   = 512;
    size_t off_fb6    = (off_acc6 + acc_bytes6 + 255) & ~(size_t)255;
    size_t fb_bytes6  = (size_t)n_in_rows * C_DIM * 2;
    size_t need_b     = off_acc6 + acc_bytes6;
    size_t need_a     = off_fb6 + fb_bytes6;

    float*  sums  = (float*)d_ws;
    __half* acc   = (__half*)((char*)d_ws + off_acc6);
    bf16_t* fbf16 = (bf16_t*)((char*)d_ws + off_fb6);

    const int rows_per_block = 512;
    dim3 g1((P + rows_per_block - 1) / rows_per_block, K3);

    if (ws_size >= need_b) {
        const int use_bf16 = (ws_size >= need_a) ? 1 : 0;

        hipMemsetAsync(d_ws, 0, off_acc6 + acc_bytes6, stream);
        if (use_bf16)
            k_fprep<<<(n_in_rows * 16 + 255) / 256, 256, 0, stream>>>(
                features, fbf16, n_in_rows * 16);

        k1_fp16<<<g1, 256, 0, stream>>>(features, fbf16, weight, pairs_in,
                                        pairs_out, acc, P, rows_per_block,
                                        use_bf16);

        k2_stats_h<<<dim3(256), 256, 0, stream>>>(acc, sums, n_out);
        k3_bn_relu_h<<<dim3(512), 256, 0, stream>>>(acc, out, sums, gamma,
                                                    beta, n_out);
    } else {
        hipMemsetAsync(d_out, 0, (size_t)out_size * sizeof(float), stream);
        hipMemsetAsync(d_ws, 0, 512, stream);

        k1_scatter_gemm<<<g1, 256, 0, stream>>>(features, weight, pairs_in,
                                                pairs_out, out, P, rows_per_block);
        k2_stats<<<dim3(1024), 256, 0, stream>>>(out, sums, n_out);
        k3_bn_relu<<<dim3(1024), 256, 0, stream>>>(out, sums, gamma, beta, n_out);
    }
}

// Round 8
// 387.671 us; speedup vs baseline: 1.6595x; 1.6595x over previous
//
#include <hip/hip_runtime.h>
#include <hip/hip_fp16.h>

// SparseConvTransposeBlock, round 16: R6 pipeline, 3 dispatches.
//
// Binned family (R9-R15) is dead: binning pass alone costs 150-210us
// (request-rate bound) and every merge mechanism measured slow (LDS atomics
// ~58cy/op; LDS merge loop 426us; latency-bound register slots 374us).
// Global fp16 atomics write through to HBM per-op (WRITE 270MB invariant,
// clustered or not) -> k1's 226us at 387MB/1.72TB/s is the practical floor.
//
// R12 ledger re-audit: the ticket-barrier fused epilogue (k23_fused) was
// FAST (~15-30us) — R12's real path ran ~255us hidden behind the piggyback
// experiment. R0 ledger shows ~19us/dispatch launch gap (94us over 5
// dispatches). So: cut to 3 dispatches:
//   k_prep (zero sums+ticket+acc  +  features->bf16 convert)
//   k1_fp16 (proven, untouched, 226us)
//   k23_fused (proven in R12; 512 co-resident blocks)
//
// Fallbacks: R6 5-dispatch path (small ws), R1 fp32 path (tiny ws).

#define C_DIM 64
#define LDS_STRIDE 72   // bf16 elems per Wt row: 64 + 8 pad
#define ROW_STRIDE 68   // fp32 elems per scratch row: 64 + 4 pad

typedef __bf16 bf16_t;
typedef bf16_t bf16x4 __attribute__((ext_vector_type(4)));
typedef bf16_t bf16x8 __attribute__((ext_vector_type(8)));
typedef float floatx4 __attribute__((ext_vector_type(4)));

// -------- prep: zero sums(128f)+ticket + fp16 acc, convert features->bf16
__global__ __launch_bounds__(256)
void k_prep(const float* __restrict__ f, bf16_t* __restrict__ fb,
            float4* __restrict__ accz, float* __restrict__ hdr,
            int total4, int accz4)
{
    int i = blockIdx.x * 256 + threadIdx.x;
    int stride = gridDim.x * 256;
    if (i < 136) hdr[i] = 0.f;                 // sums[128] + ticket + pad
    for (int j = i; j < total4; j += stride) {
        float4 v = ((const float4*)f)[j];
        bf16x4 o;
        o[0] = (bf16_t)v.x; o[1] = (bf16_t)v.y;
        o[2] = (bf16_t)v.z; o[3] = (bf16_t)v.w;
        ((bf16x4*)fb)[j] = o;
    }
    float4 z = {0.f, 0.f, 0.f, 0.f};
    for (int j = i; j < accz4; j += stride) accz[j] = z;
}

// ================= R6 main kernel (proven, 226us) ===========================
__global__ __launch_bounds__(256)
void k1_fp16(const float* __restrict__ features,
             const bf16_t* __restrict__ fbf16,
             const float* __restrict__ weight,
             const int* __restrict__ pairs_in,
             const int* __restrict__ pairs_out,
             __half* __restrict__ acc,
             int P, int rows_per_block, int use_bf16)
{
    __shared__ bf16_t Wt[C_DIM * LDS_STRIDE];
    __shared__ float  scratch[4][16 * ROW_STRIDE];

    const int k   = blockIdx.y;
    const int tid = threadIdx.x;

    const float* Wk = weight + (size_t)k * C_DIM * C_DIM;
    for (int i = tid; i < C_DIM * C_DIM; i += 256) {
        int c = i >> 6, d = i & 63;
        Wt[d * LDS_STRIDE + c] = (bf16_t)Wk[i];
    }
    __syncthreads();

    const int wave = tid >> 6;
    const int lane = tid & 63;
    const int quad = lane >> 4;
    const int col  = lane & 15;
    const int sub  = lane >> 5;
    const int c2   = lane & 31;
    float* ls = &scratch[wave][0];

    bf16x8 bfrag[2][4];
    #pragma unroll
    for (int ks = 0; ks < 2; ++ks)
        #pragma unroll
        for (int nt = 0; nt < 4; ++nt)
            bfrag[ks][nt] =
                *(const bf16x8*)&Wt[(col + 16 * nt) * LDS_STRIDE + quad * 8 + 32 * ks];

    const int* __restrict__ pin  = pairs_in  + (size_t)k * P;
    const int* __restrict__ pout = pairs_out + (size_t)k * P;

    const int p0   = blockIdx.x * rows_per_block;
    const int pend = min(p0 + rows_per_block, P);

    for (int base = p0 + wave * 16; base < pend; base += 64) {
        int prow    = base + col;
        int clamped = (prow < pend) ? prow : (pend - 1);
        int in_idx  = pin[clamped];
        int out_idx = pout[clamped];

        bf16x8 a0, a1;
        if (use_bf16) {
            const bf16_t* src = fbf16 + (size_t)in_idx * C_DIM + quad * 8;
            a0 = *(const bf16x8*)(src);
            a1 = *(const bf16x8*)(src + 32);
        } else {
            const float* src = features + (size_t)in_idx * C_DIM + quad * 8;
            float4 f0 = *(const float4*)(src);
            float4 f1 = *(const float4*)(src + 4);
            float4 f2 = *(const float4*)(src + 32);
            float4 f3 = *(const float4*)(src + 36);
            a0[0] = (bf16_t)f0.x; a0[1] = (bf16_t)f0.y; a0[2] = (bf16_t)f0.z; a0[3] = (bf16_t)f0.w;
            a0[4] = (bf16_t)f1.x; a0[5] = (bf16_t)f1.y; a0[6] = (bf16_t)f1.z; a0[7] = (bf16_t)f1.w;
            a1[0] = (bf16_t)f2.x; a1[1] = (bf16_t)f2.y; a1[2] = (bf16_t)f2.z; a1[3] = (bf16_t)f2.w;
            a1[4] = (bf16_t)f3.x; a1[5] = (bf16_t)f3.y; a1[6] = (bf16_t)f3.z; a1[7] = (bf16_t)f3.w;
        }

        floatx4 acc0 = {0.f, 0.f, 0.f, 0.f};
        floatx4 acc1 = {0.f, 0.f, 0.f, 0.f};
        floatx4 acc2 = {0.f, 0.f, 0.f, 0.f};
        floatx4 acc3 = {0.f, 0.f, 0.f, 0.f};

        acc0 = __builtin_amdgcn_mfma_f32_16x16x32_bf16(a0, bfrag[0][0], acc0, 0, 0, 0);
        acc0 = __builtin_amdgcn_mfma_f32_16x16x32_bf16(a1, bfrag[1][0], acc0, 0, 0, 0);
        acc1 = __builtin_amdgcn_mfma_f32_16x16x32_bf16(a0, bfrag[0][1], acc1, 0, 0, 0);
        acc1 = __builtin_amdgcn_mfma_f32_16x16x32_bf16(a1, bfrag[1][1], acc1, 0, 0, 0);
        acc2 = __builtin_amdgcn_mfma_f32_16x16x32_bf16(a0, bfrag[0][2], acc2, 0, 0, 0);
        acc2 = __builtin_amdgcn_mfma_f32_16x16x32_bf16(a1, bfrag[1][2], acc2, 0, 0, 0);
        acc3 = __builtin_amdgcn_mfma_f32_16x16x32_bf16(a0, bfrag[0][3], acc3, 0, 0, 0);
        acc3 = __builtin_amdgcn_mfma_f32_16x16x32_bf16(a1, bfrag[1][3], acc3, 0, 0, 0);

        #pragma unroll
        for (int r = 0; r < 4; ++r) {
            int m = quad * 4 + r;
            ls[m * ROW_STRIDE + col +  0] = acc0[r];
            ls[m * ROW_STRIDE + col + 16] = acc1[r];
            ls[m * ROW_STRIDE + col + 32] = acc2[r];
            ls[m * ROW_STRIDE + col + 48] = acc3[r];
        }
        asm volatile("s_waitcnt lgkmcnt(0)" ::: "memory");

        #pragma unroll
        for (int m2 = 0; m2 < 8; ++m2) {
            int m = m2 * 2 + sub;
            float2 v = *(const float2*)&ls[m * ROW_STRIDE + 2 * c2];
            __half2 h = __floats2half2_rn(v.x, v.y);
            int g = __shfl(out_idx, m);
            if (base + m < pend)
                unsafeAtomicAdd((__half2*)(acc + (size_t)g * C_DIM + 2 * c2), h);
        }
    }
}

// ---------------- fused stats + ticket barrier + BN/ReLU (proven R12) -------
// nblocks co-resident blocks (512 blocks = 2/CU, trivially resident).
__global__ __launch_bounds__(256)
void k23_fused(const __half* __restrict__ acc, float* __restrict__ out,
               float* __restrict__ sums, int* __restrict__ ticket,
               const float* __restrict__ gamma, const float* __restrict__ beta,
               int n_rows, int nblocks)
{
    const int tid = threadIdx.x;
    const int c8  = tid & 7;
    const int sub = tid >> 3;

    // phase 1: partial per-channel sum / sumsq
    float s[8] = {0,0,0,0,0,0,0,0}, q[8] = {0,0,0,0,0,0,0,0};
    for (int r = blockIdx.x * 32 + sub; r < n_rows; r += nblocks * 32) {
        float4 v = *(const float4*)&acc[(size_t)r * C_DIM + c8 * 8];
        const __half2* h = (const __half2*)&v;
        #pragma unroll
        for (int j = 0; j < 4; ++j) {
            float x = __half2float(h[j].x), y = __half2float(h[j].y);
            s[2*j]   += x; q[2*j]   += x * x;
            s[2*j+1] += y; q[2*j+1] += y * y;
        }
    }
    __shared__ float red[128];
    if (tid < 128) red[tid] = 0.f;
    __syncthreads();
    #pragma unroll
    for (int j = 0; j < 8; ++j) {
        atomicAdd(&red[c8 * 8 + j], s[j]);
        atomicAdd(&red[64 + c8 * 8 + j], q[j]);
    }
    __syncthreads();
    if (tid < 128) unsafeAtomicAdd(&sums[tid], red[tid]);
    __syncthreads();

    // ticket barrier (device-scope atomics; spin on one lane)
    if (tid == 0) {
        __threadfence();
        atomicAdd(ticket, 1);
        while (atomicAdd(ticket, 0) < nblocks)
            __builtin_amdgcn_s_sleep(1);
    }
    __syncthreads();

    // snapshot sums via atomic-reads (coherence point, XCD-safe)
    __shared__ float snap[128];
    if (tid < 128) snap[tid] = unsafeAtomicAdd(&sums[tid], 0.0f);
    __syncthreads();

    float inv_n = 1.0f / (float)n_rows;
    float sc[8], sh[8];
    #pragma unroll
    for (int j = 0; j < 8; ++j) {
        int ch    = c8 * 8 + j;
        float m   = snap[ch] * inv_n;
        float var = snap[64 + ch] * inv_n - m * m;
        float inv = rsqrtf(var + 1e-5f);
        float g   = gamma[ch] * inv;
        sc[j] = g;
        sh[j] = beta[ch] - m * g;
    }

    // phase 2: normalize + ReLU
    size_t total = (size_t)n_rows * 8;   // halfx8 octets
    for (size_t i = blockIdx.x * 256 + tid; i < total; i += (size_t)nblocks * 256) {
        float4 v = ((const float4*)acc)[i];
        const __half2* h = (const __half2*)&v;
        float4 o0, o1;
        o0.x = fmaxf(__half2float(h[0].x) * sc[0] + sh[0], 0.f);
        o0.y = fmaxf(__half2float(h[0].y) * sc[1] + sh[1], 0.f);
        o0.z = fmaxf(__half2float(h[1].x) * sc[2] + sh[2], 0.f);
        o0.w = fmaxf(__half2float(h[1].y) * sc[3] + sh[3], 0.f);
        o1.x = fmaxf(__half2float(h[2].x) * sc[4] + sh[4], 0.f);
        o1.y = fmaxf(__half2float(h[2].y) * sc[5] + sh[5], 0.f);
        o1.z = fmaxf(__half2float(h[3].x) * sc[6] + sh[6], 0.f);
        o1.w = fmaxf(__half2float(h[3].y) * sc[7] + sh[7], 0.f);
        ((float4*)out)[2 * i]     = o0;
        ((float4*)out)[2 * i + 1] = o1;
    }
}

// ============== fallback epilogue (R6 split kernels, proven) ================
__global__ __launch_bounds__(256)
void k2_stats_h(const __half* __restrict__ acc, float* __restrict__ sums,
                int n_rows)
{
    const int tid = threadIdx.x;
    const int c8  = tid & 7;
    const int sub = tid >> 3;

    float s[8] = {0,0,0,0,0,0,0,0}, q[8] = {0,0,0,0,0,0,0,0};
    for (int r = blockIdx.x * 32 + sub; r < n_rows; r += gridDim.x * 32) {
        float4 v = *(const float4*)&acc[(size_t)r * C_DIM + c8 * 8];
        const __half2* h = (const __half2*)&v;
        #pragma unroll
        for (int j = 0; j < 4; ++j) {
            float x = __half2float(h[j].x), y = __half2float(h[j].y);
            s[2*j]   += x; q[2*j]   += x * x;
            s[2*j+1] += y; q[2*j+1] += y * y;
        }
    }

    __shared__ float red[128];
    if (tid < 128) red[tid] = 0.f;
    __syncthreads();
    #pragma unroll
    for (int j = 0; j < 8; ++j) {
        atomicAdd(&red[c8 * 8 + j], s[j]);
        atomicAdd(&red[64 + c8 * 8 + j], q[j]);
    }
    __syncthreads();
    if (tid < 128) atomicAdd(&sums[tid], red[tid]);
}

__global__ __launch_bounds__(256)
void k3_bn_relu_h(const __half* __restrict__ acc, float* __restrict__ out,
                  const float* __restrict__ sums,
                  const float* __restrict__ gamma, const float* __restrict__ beta,
                  int n_rows)
{
    int tid = blockIdx.x * 256 + threadIdx.x;
    int c8  = tid & 7;
    float inv_n = 1.0f / (float)n_rows;

    float sc[8], sh[8];
    #pragma unroll
    for (int j = 0; j < 8; ++j) {
        int ch    = c8 * 8 + j;
        float m   = sums[ch] * inv_n;
        float var = sums[64 + ch] * inv_n - m * m;
        float inv = rsqrtf(var + 1e-5f);
        float g   = gamma[ch] * inv;
        sc[j] = g;
        sh[j] = beta[ch] - m * g;
    }

    size_t total = (size_t)n_rows * 8;
    for (size_t i = tid; i < total; i += (size_t)gridDim.x * 256) {
        float4 v = ((const float4*)acc)[i];
        const __half2* h = (const __half2*)&v;
        float4 o0, o1;
        o0.x = fmaxf(__half2float(h[0].x) * sc[0] + sh[0], 0.f);
        o0.y = fmaxf(__half2float(h[0].y) * sc[1] + sh[1], 0.f);
        o0.z = fmaxf(__half2float(h[1].x) * sc[2] + sh[2], 0.f);
        o0.w = fmaxf(__half2float(h[1].y) * sc[3] + sh[3], 0.f);
        o1.x = fmaxf(__half2float(h[2].x) * sc[4] + sh[4], 0.f);
        o1.y = fmaxf(__half2float(h[2].y) * sc[5] + sh[5], 0.f);
        o1.z = fmaxf(__half2float(h[3].x) * sc[6] + sh[6], 0.f);
        o1.w = fmaxf(__half2float(h[3].y) * sc[7] + sh[7], 0.f);
        ((float4*)out)[2 * i]     = o0;
        ((float4*)out)[2 * i + 1] = o1;
    }
}

// ===================== fallback (R1 path, proven) ===========================
__global__ __launch_bounds__(256)
void k1_scatter_gemm(const float* __restrict__ features,
                     const float* __restrict__ weight,
                     const int* __restrict__ pairs_in,
                     const int* __restrict__ pairs_out,
                     float* __restrict__ out,
                     int P, int rows_per_block)
{
    __shared__ bf16_t Wt[C_DIM * LDS_STRIDE];
    const int k   = blockIdx.y;
    const int tid = threadIdx.x;
    const float* Wk = weight + (size_t)k * C_DIM * C_DIM;
    for (int i = tid; i < C_DIM * C_DIM; i += 256) {
        int c = i >> 6, d = i & 63;
        Wt[d * LDS_STRIDE + c] = (bf16_t)Wk[i];
    }
    __syncthreads();
    const int wave = tid >> 6, lane = tid & 63, quad = lane >> 4, col = lane & 15;
    bf16x8 bfrag[2][4];
    #pragma unroll
    for (int ks = 0; ks < 2; ++ks)
        #pragma unroll
        for (int nt = 0; nt < 4; ++nt)
            bfrag[ks][nt] =
                *(const bf16x8*)&Wt[(col + 16 * nt) * LDS_STRIDE + quad * 8 + 32 * ks];
    const int* __restrict__ pin  = pairs_in  + (size_t)k * P;
    const int* __restrict__ pout = pairs_out + (size_t)k * P;
    const int p0   = blockIdx.x * rows_per_block;
    const int pend = min(p0 + rows_per_block, P);
    for (int base = p0 + wave * 16; base < pend; base += 64) {
        int prow    = base + col;
        int clamped = (prow < pend) ? prow : (pend - 1);
        int in_idx  = pin[clamped];
        int out_idx = pout[clamped];
        const float* src = features + (size_t)in_idx * C_DIM + quad * 8;
        float4 f0 = *(const float4*)(src);
        float4 f1 = *(const float4*)(src + 4);
        float4 f2 = *(const float4*)(src + 32);
        float4 f3 = *(const float4*)(src + 36);
        bf16x8 a0, a1;
        a0[0] = (bf16_t)f0.x; a0[1] = (bf16_t)f0.y; a0[2] = (bf16_t)f0.z; a0[3] = (bf16_t)f0.w;
        a0[4] = (bf16_t)f1.x; a0[5] = (bf16_t)f1.y; a0[6] = (bf16_t)f1.z; a0[7] = (bf16_t)f1.w;
        a1[0] = (bf16_t)f2.x; a1[1] = (bf16_t)f2.y; a1[2] = (bf16_t)f2.z; a1[3] = (bf16_t)f2.w;
        a1[4] = (bf16_t)f3.x; a1[5] = (bf16_t)f3.y; a1[6] = (bf16_t)f3.z; a1[7] = (bf16_t)f3.w;
        floatx4 acc0 = {0.f,0.f,0.f,0.f}, acc1 = {0.f,0.f,0.f,0.f};
        floatx4 acc2 = {0.f,0.f,0.f,0.f}, acc3 = {0.f,0.f,0.f,0.f};
        acc0 = __builtin_amdgcn_mfma_f32_16x16x32_bf16(a0, bfrag[0][0], acc0, 0, 0, 0);
        acc0 = __builtin_amdgcn_mfma_f32_16x16x32_bf16(a1, bfrag[1][0], acc0, 0, 0, 0);
        acc1 = __builtin_amdgcn_mfma_f32_16x16x32_bf16(a0, bfrag[0][1], acc1, 0, 0, 0);
        acc1 = __builtin_amdgcn_mfma_f32_16x16x32_bf16(a1, bfrag[1][1], acc1, 0, 0, 0);
        acc2 = __builtin_amdgcn_mfma_f32_16x16x32_bf16(a0, bfrag[0][2], acc2, 0, 0, 0);
        acc2 = __builtin_amdgcn_mfma_f32_16x16x32_bf16(a1, bfrag[1][2], acc2, 0, 0, 0);
        acc3 = __builtin_amdgcn_mfma_f32_16x16x32_bf16(a0, bfrag[0][3], acc3, 0, 0, 0);
        acc3 = __builtin_amdgcn_mfma_f32_16x16x32_bf16(a1, bfrag[1][3], acc3, 0, 0, 0);
        #pragma unroll
        for (int r = 0; r < 4; ++r) {
            int m = quad * 4 + r;
            int g = __shfl(out_idx, m);
            if (base + m < pend) {
                float* dst = out + (size_t)g * C_DIM + col;
                unsafeAtomicAdd(dst +  0, acc0[r]);
                unsafeAtomicAdd(dst + 16, acc1[r]);
                unsafeAtomicAdd(dst + 32, acc2[r]);
                unsafeAtomicAdd(dst + 48, acc3[r]);
            }
        }
    }
}

__global__ __launch_bounds__(256)
void k2_stats(const float* __restrict__ acc, float* __restrict__ sums, int n_rows)
{
    int tid = threadIdx.x;
    int ch  = tid & 63;
    int sub = tid >> 6;
    float s = 0.f, s2 = 0.f;
    for (int r = blockIdx.x * 4 + sub; r < n_rows; r += gridDim.x * 4) {
        float v = acc[(size_t)r * C_DIM + ch];
        s  += v;
        s2 += v * v;
    }
    __shared__ float red[256];
    red[tid] = s;
    __syncthreads();
    if (tid < 64) {
        float t = red[tid] + red[tid + 64] + red[tid + 128] + red[tid + 192];
        atomicAdd(&sums[ch], t);
    }
    __syncthreads();
    red[tid] = s2;
    __syncthreads();
    if (tid < 64) {
        float t = red[tid] + red[tid + 64] + red[tid + 128] + red[tid + 192];
        atomicAdd(&sums[64 + ch], t);
    }
}

__global__ __launch_bounds__(256)
void k3_bn_relu(float* __restrict__ out, const float* __restrict__ sums,
                const float* __restrict__ gamma, const float* __restrict__ beta,
                int n_rows)
{
    int tid = blockIdx.x * 256 + threadIdx.x;
    int ch0 = (tid * 4) & 63;
    float inv_n = 1.0f / (float)n_rows;
    float sc[4], sh[4];
    #pragma unroll
    for (int j = 0; j < 4; ++j) {
        int ch    = ch0 + j;
        float m   = sums[ch] * inv_n;
        float var = sums[64 + ch] * inv_n - m * m;
        float inv = rsqrtf(var + 1e-5f);
        float g   = gamma[ch] * inv;
        sc[j] = g;
        sh[j] = beta[ch] - m * g;
    }
    size_t total = (size_t)n_rows * C_DIM / 4;
    for (size_t i = tid; i < total; i += (size_t)gridDim.x * 256) {
        float4 v = ((const float4*)out)[i];
        v.x = fmaxf(v.x * sc[0] + sh[0], 0.f);
        v.y = fmaxf(v.y * sc[1] + sh[1], 0.f);
        v.z = fmaxf(v.z * sc[2] + sh[2], 0.f);
        v.w = fmaxf(v.w * sc[3] + sh[3], 0.f);
        ((float4*)out)[i] = v;
    }
}

// ============================================================================
extern "C" void kernel_launch(void* const* d_in, const int* in_sizes, int n_in,
                              void* d_out, int out_size, void* d_ws, size_t ws_size,
                              hipStream_t stream)
{
    const float* features  = (const float*)d_in[0];
    const float* weight    = (const float*)d_in[1];
    // d_in[2] = bias (cancels in training-mode BN)
    const float* gamma     = (const float*)d_in[3];
    const float* beta      = (const float*)d_in[4];
    const int*   pairs_in  = (const int*)d_in[5];
    const int*   pairs_out = (const int*)d_in[6];

    const int n_out     = out_size / C_DIM;
    const int n_in_rows = in_sizes[0] / C_DIM;
    const int K3        = in_sizes[1] / (C_DIM * C_DIM);
    const int P         = in_sizes[5] / K3;

    float* out = (float*)d_out;

    // ws layout: sums[128f](512B) | ticket(4B)+pad | acc fp16 @1024 | fb bf16
    const size_t off_acc = 1024;
    size_t acc_bytes = (size_t)n_out * C_DIM * 2;
    size_t off_fb    = (off_acc + acc_bytes + 255) & ~(size_t)255;
    size_t fb_bytes  = (size_t)n_in_rows * C_DIM * 2;
    size_t need_b    = off_acc + acc_bytes;
    size_t need_a    = off_fb + fb_bytes;

    float*  sums   = (float*)d_ws;
    int*    ticket = (int*)((char*)d_ws + 512);
    __half* acc    = (__half*)((char*)d_ws + off_acc);
    bf16_t* fbf16  = (bf16_t*)((char*)d_ws + off_fb);

    const int rows_per_block = 512;
    dim3 g1((P + rows_per_block - 1) / rows_per_block, K3);

    if (ws_size >= need_a) {
        // ---- 3-dispatch primary path ----
        k_prep<<<dim3(2048), 256, 0, stream>>>(features, fbf16,
                                               (float4*)acc, (float*)d_ws,
                                               n_in_rows * 16,
                                               (int)(acc_bytes / 16));

        k1_fp16<<<g1, 256, 0, stream>>>(features, fbf16, weight, pairs_in,
                                        pairs_out, acc, P, rows_per_block, 1);

        k23_fused<<<dim3(512), 256, 0, stream>>>(acc, out, sums, ticket,
                                                 gamma, beta, n_out, 512);
    } else if (ws_size >= need_b) {
        // ---- R6 path without bf16 table (f32 feature loads) ----
        hipMemsetAsync(d_ws, 0, off_acc + acc_bytes, stream);
        k1_fp16<<<g1, 256, 0, stream>>>(features, fbf16, weight, pairs_in,
                                        pairs_out, acc, P, rows_per_block, 0);
        k2_stats_h<<<dim3(256), 256, 0, stream>>>(acc, sums, n_out);
        k3_bn_relu_h<<<dim3(512), 256, 0, stream>>>(acc, out, sums, gamma,
                                                    beta, n_out);
    } else {
        // ---- R1 fp32 path ----
        hipMemsetAsync(d_out, 0, (size_t)out_size * sizeof(float), stream);
        hipMemsetAsync(d_ws, 0, 512, stream);

        k1_scatter_gemm<<<g1, 256, 0, stream>>>(features, weight, pairs_in,
                                                pairs_out, out, P, rows_per_block);
        k2_stats<<<dim3(1024), 256, 0, stream>>>(out, sums, n_out);
        k3_bn_relu<<<dim3(1024), 256, 0, stream>>>(out, sums, gamma, beta, n_out);
    }
}

// Round 9
// 356.629 us; speedup vs baseline: 1.8040x; 1.0870x over previous
//
#include <hip/hip_runtime.h>
#include <hip/hip_fp16.h>

// SparseConvTransposeBlock, round 17: 4-dispatch pipeline, all-proven parts.
//
// R16 verdict: k23_fused's ticket barrier cost ~120us (512 spinners on one
// atomic line across 8 XCDs) — fused epilogue REVERTED to split k2/k3.
// Kept from R16: k_prep (fused zero+convert, one dispatch+gap saved).
//
// k1_fp16 is at the atomic write-through drain floor (WRITE 270MB invariant
// across clustered/unclustered R6/R13; LDS-atomic, LDS-merge, reg-slot
// merge alternatives all measured slower in R9-R15). 387MB @ ~1.76TB/s
// effective = 220us.
//
// Pipeline: k_prep | k1_fp16 | k2_stats_h(512) | k3_bn_relu_h(1024).
// Fallbacks: R6-no-table path (small ws), R1 fp32 path (tiny ws).

#define C_DIM 64
#define LDS_STRIDE 72   // bf16 elems per Wt row: 64 + 8 pad
#define ROW_STRIDE 68   // fp32 elems per scratch row: 64 + 4 pad

typedef __bf16 bf16_t;
typedef bf16_t bf16x4 __attribute__((ext_vector_type(4)));
typedef bf16_t bf16x8 __attribute__((ext_vector_type(8)));
typedef float floatx4 __attribute__((ext_vector_type(4)));

// -------- prep: zero sums(128f) + fp16 acc, convert features->bf16
__global__ __launch_bounds__(256)
void k_prep(const float* __restrict__ f, bf16_t* __restrict__ fb,
            float4* __restrict__ accz, float* __restrict__ hdr,
            int total4, int accz4)
{
    int i = blockIdx.x * 256 + threadIdx.x;
    int stride = gridDim.x * 256;
    if (i < 136) hdr[i] = 0.f;                 // sums[128] + pad
    for (int j = i; j < total4; j += stride) {
        float4 v = ((const float4*)f)[j];
        bf16x4 o;
        o[0] = (bf16_t)v.x; o[1] = (bf16_t)v.y;
        o[2] = (bf16_t)v.z; o[3] = (bf16_t)v.w;
        ((bf16x4*)fb)[j] = o;
    }
    float4 z = {0.f, 0.f, 0.f, 0.f};
    for (int j = i; j < accz4; j += stride) accz[j] = z;
}

// ================= R6 main kernel (proven, 220us) ===========================
__global__ __launch_bounds__(256)
void k1_fp16(const float* __restrict__ features,
             const bf16_t* __restrict__ fbf16,
             const float* __restrict__ weight,
             const int* __restrict__ pairs_in,
             const int* __restrict__ pairs_out,
             __half* __restrict__ acc,
             int P, int rows_per_block, int use_bf16)
{
    __shared__ bf16_t Wt[C_DIM * LDS_STRIDE];
    __shared__ float  scratch[4][16 * ROW_STRIDE];

    const int k   = blockIdx.y;
    const int tid = threadIdx.x;

    const float* Wk = weight + (size_t)k * C_DIM * C_DIM;
    for (int i = tid; i < C_DIM * C_DIM; i += 256) {
        int c = i >> 6, d = i & 63;
        Wt[d * LDS_STRIDE + c] = (bf16_t)Wk[i];
    }
    __syncthreads();

    const int wave = tid >> 6;
    const int lane = tid & 63;
    const int quad = lane >> 4;
    const int col  = lane & 15;
    const int sub  = lane >> 5;
    const int c2   = lane & 31;
    float* ls = &scratch[wave][0];

    bf16x8 bfrag[2][4];
    #pragma unroll
    for (int ks = 0; ks < 2; ++ks)
        #pragma unroll
        for (int nt = 0; nt < 4; ++nt)
            bfrag[ks][nt] =
                *(const bf16x8*)&Wt[(col + 16 * nt) * LDS_STRIDE + quad * 8 + 32 * ks];

    const int* __restrict__ pin  = pairs_in  + (size_t)k * P;
    const int* __restrict__ pout = pairs_out + (size_t)k * P;

    const int p0   = blockIdx.x * rows_per_block;
    const int pend = min(p0 + rows_per_block, P);

    for (int base = p0 + wave * 16; base < pend; base += 64) {
        int prow    = base + col;
        int clamped = (prow < pend) ? prow : (pend - 1);
        int in_idx  = pin[clamped];
        int out_idx = pout[clamped];

        bf16x8 a0, a1;
        if (use_bf16) {
            const bf16_t* src = fbf16 + (size_t)in_idx * C_DIM + quad * 8;
            a0 = *(const bf16x8*)(src);
            a1 = *(const bf16x8*)(src + 32);
        } else {
            const float* src = features + (size_t)in_idx * C_DIM + quad * 8;
            float4 f0 = *(const float4*)(src);
            float4 f1 = *(const float4*)(src + 4);
            float4 f2 = *(const float4*)(src + 32);
            float4 f3 = *(const float4*)(src + 36);
            a0[0] = (bf16_t)f0.x; a0[1] = (bf16_t)f0.y; a0[2] = (bf16_t)f0.z; a0[3] = (bf16_t)f0.w;
            a0[4] = (bf16_t)f1.x; a0[5] = (bf16_t)f1.y; a0[6] = (bf16_t)f1.z; a0[7] = (bf16_t)f1.w;
            a1[0] = (bf16_t)f2.x; a1[1] = (bf16_t)f2.y; a1[2] = (bf16_t)f2.z; a1[3] = (bf16_t)f2.w;
            a1[4] = (bf16_t)f3.x; a1[5] = (bf16_t)f3.y; a1[6] = (bf16_t)f3.z; a1[7] = (bf16_t)f3.w;
        }

        floatx4 acc0 = {0.f, 0.f, 0.f, 0.f};
        floatx4 acc1 = {0.f, 0.f, 0.f, 0.f};
        floatx4 acc2 = {0.f, 0.f, 0.f, 0.f};
        floatx4 acc3 = {0.f, 0.f, 0.f, 0.f};

        acc0 = __builtin_amdgcn_mfma_f32_16x16x32_bf16(a0, bfrag[0][0], acc0, 0, 0, 0);
        acc0 = __builtin_amdgcn_mfma_f32_16x16x32_bf16(a1, bfrag[1][0], acc0, 0, 0, 0);
        acc1 = __builtin_amdgcn_mfma_f32_16x16x32_bf16(a0, bfrag[0][1], acc1, 0, 0, 0);
        acc1 = __builtin_amdgcn_mfma_f32_16x16x32_bf16(a1, bfrag[1][1], acc1, 0, 0, 0);
        acc2 = __builtin_amdgcn_mfma_f32_16x16x32_bf16(a0, bfrag[0][2], acc2, 0, 0, 0);
        acc2 = __builtin_amdgcn_mfma_f32_16x16x32_bf16(a1, bfrag[1][2], acc2, 0, 0, 0);
        acc3 = __builtin_amdgcn_mfma_f32_16x16x32_bf16(a0, bfrag[0][3], acc3, 0, 0, 0);
        acc3 = __builtin_amdgcn_mfma_f32_16x16x32_bf16(a1, bfrag[1][3], acc3, 0, 0, 0);

        #pragma unroll
        for (int r = 0; r < 4; ++r) {
            int m = quad * 4 + r;
            ls[m * ROW_STRIDE + col +  0] = acc0[r];
            ls[m * ROW_STRIDE + col + 16] = acc1[r];
            ls[m * ROW_STRIDE + col + 32] = acc2[r];
            ls[m * ROW_STRIDE + col + 48] = acc3[r];
        }
        asm volatile("s_waitcnt lgkmcnt(0)" ::: "memory");

        #pragma unroll
        for (int m2 = 0; m2 < 8; ++m2) {
            int m = m2 * 2 + sub;
            float2 v = *(const float2*)&ls[m * ROW_STRIDE + 2 * c2];
            __half2 h = __floats2half2_rn(v.x, v.y);
            int g = __shfl(out_idx, m);
            if (base + m < pend)
                unsafeAtomicAdd((__half2*)(acc + (size_t)g * C_DIM + 2 * c2), h);
        }
    }
}

// ---------------------- per-channel sum / sumsq over the fp16 accumulator
__global__ __launch_bounds__(256)
void k2_stats_h(const __half* __restrict__ acc, float* __restrict__ sums,
                int n_rows)
{
    const int tid = threadIdx.x;
    const int c8  = tid & 7;    // channel octet
    const int sub = tid >> 3;   // 32 rows per block pass

    float s[8] = {0,0,0,0,0,0,0,0}, q[8] = {0,0,0,0,0,0,0,0};
    for (int r = blockIdx.x * 32 + sub; r < n_rows; r += gridDim.x * 32) {
        float4 v = *(const float4*)&acc[(size_t)r * C_DIM + c8 * 8];
        const __half2* h = (const __half2*)&v;
        #pragma unroll
        for (int j = 0; j < 4; ++j) {
            float x = __half2float(h[j].x), y = __half2float(h[j].y);
            s[2*j]   += x; q[2*j]   += x * x;
            s[2*j+1] += y; q[2*j+1] += y * y;
        }
    }

    __shared__ float red[128];
    if (tid < 128) red[tid] = 0.f;
    __syncthreads();
    #pragma unroll
    for (int j = 0; j < 8; ++j) {
        atomicAdd(&red[c8 * 8 + j], s[j]);
        atomicAdd(&red[64 + c8 * 8 + j], q[j]);
    }
    __syncthreads();
    if (tid < 128) atomicAdd(&sums[tid], red[tid]);
}

// ------------------------- BN normalize + ReLU: fp16 acc -> fp32 out
__global__ __launch_bounds__(256)
void k3_bn_relu_h(const __half* __restrict__ acc, float* __restrict__ out,
                  const float* __restrict__ sums,
                  const float* __restrict__ gamma, const float* __restrict__ beta,
                  int n_rows)
{
    int tid = blockIdx.x * 256 + threadIdx.x;
    int c8  = tid & 7;                   // fixed channel octet per thread
    float inv_n = 1.0f / (float)n_rows;

    float sc[8], sh[8];
    #pragma unroll
    for (int j = 0; j < 8; ++j) {
        int ch    = c8 * 8 + j;
        float m   = sums[ch] * inv_n;
        float var = sums[64 + ch] * inv_n - m * m;
        float inv = rsqrtf(var + 1e-5f);
        float g   = gamma[ch] * inv;
        sc[j] = g;
        sh[j] = beta[ch] - m * g;
    }

    size_t total = (size_t)n_rows * 8;   // halfx8 octets
    for (size_t i = tid; i < total; i += (size_t)gridDim.x * 256) {
        float4 v = ((const float4*)acc)[i];
        const __half2* h = (const __half2*)&v;
        float4 o0, o1;
        o0.x = fmaxf(__half2float(h[0].x) * sc[0] + sh[0], 0.f);
        o0.y = fmaxf(__half2float(h[0].y) * sc[1] + sh[1], 0.f);
        o0.z = fmaxf(__half2float(h[1].x) * sc[2] + sh[2], 0.f);
        o0.w = fmaxf(__half2float(h[1].y) * sc[3] + sh[3], 0.f);
        o1.x = fmaxf(__half2float(h[2].x) * sc[4] + sh[4], 0.f);
        o1.y = fmaxf(__half2float(h[2].y) * sc[5] + sh[5], 0.f);
        o1.z = fmaxf(__half2float(h[3].x) * sc[6] + sh[6], 0.f);
        o1.w = fmaxf(__half2float(h[3].y) * sc[7] + sh[7], 0.f);
        ((float4*)out)[2 * i]     = o0;
        ((float4*)out)[2 * i + 1] = o1;
    }
}

// ===================== fallback (R1 path, proven) ===========================
__global__ __launch_bounds__(256)
void k1_scatter_gemm(const float* __restrict__ features,
                     const float* __restrict__ weight,
                     const int* __restrict__ pairs_in,
                     const int* __restrict__ pairs_out,
                     float* __restrict__ out,
                     int P, int rows_per_block)
{
    __shared__ bf16_t Wt[C_DIM * LDS_STRIDE];
    const int k   = blockIdx.y;
    const int tid = threadIdx.x;
    const float* Wk = weight + (size_t)k * C_DIM * C_DIM;
    for (int i = tid; i < C_DIM * C_DIM; i += 256) {
        int c = i >> 6, d = i & 63;
        Wt[d * LDS_STRIDE + c] = (bf16_t)Wk[i];
    }
    __syncthreads();
    const int wave = tid >> 6, lane = tid & 63, quad = lane >> 4, col = lane & 15;
    bf16x8 bfrag[2][4];
    #pragma unroll
    for (int ks = 0; ks < 2; ++ks)
        #pragma unroll
        for (int nt = 0; nt < 4; ++nt)
            bfrag[ks][nt] =
                *(const bf16x8*)&Wt[(col + 16 * nt) * LDS_STRIDE + quad * 8 + 32 * ks];
    const int* __restrict__ pin  = pairs_in  + (size_t)k * P;
    const int* __restrict__ pout = pairs_out + (size_t)k * P;
    const int p0   = blockIdx.x * rows_per_block;
    const int pend = min(p0 + rows_per_block, P);
    for (int base = p0 + wave * 16; base < pend; base += 64) {
        int prow    = base + col;
        int clamped = (prow < pend) ? prow : (pend - 1);
        int in_idx  = pin[clamped];
        int out_idx = pout[clamped];
        const float* src = features + (size_t)in_idx * C_DIM + quad * 8;
        float4 f0 = *(const float4*)(src);
        float4 f1 = *(const float4*)(src + 4);
        float4 f2 = *(const float4*)(src + 32);
        float4 f3 = *(const float4*)(src + 36);
        bf16x8 a0, a1;
        a0[0] = (bf16_t)f0.x; a0[1] = (bf16_t)f0.y; a0[2] = (bf16_t)f0.z; a0[3] = (bf16_t)f0.w;
        a0[4] = (bf16_t)f1.x; a0[5] = (bf16_t)f1.y; a0[6] = (bf16_t)f1.z; a0[7] = (bf16_t)f1.w;
        a1[0] = (bf16_t)f2.x; a1[1] = (bf16_t)f2.y; a1[2] = (bf16_t)f2.z; a1[3] = (bf16_t)f2.w;
        a1[4] = (bf16_t)f3.x; a1[5] = (bf16_t)f3.y; a1[6] = (bf16_t)f3.z; a1[7] = (bf16_t)f3.w;
        floatx4 acc0 = {0.f,0.f,0.f,0.f}, acc1 = {0.f,0.f,0.f,0.f};
        floatx4 acc2 = {0.f,0.f,0.f,0.f}, acc3 = {0.f,0.f,0.f,0.f};
        acc0 = __builtin_amdgcn_mfma_f32_16x16x32_bf16(a0, bfrag[0][0], acc0, 0, 0, 0);
        acc0 = __builtin_amdgcn_mfma_f32_16x16x32_bf16(a1, bfrag[1][0], acc0, 0, 0, 0);
        acc1 = __builtin_amdgcn_mfma_f32_16x16x32_bf16(a0, bfrag[0][1], acc1, 0, 0, 0);
        acc1 = __builtin_amdgcn_mfma_f32_16x16x32_bf16(a1, bfrag[1][1], acc1, 0, 0, 0);
        acc2 = __builtin_amdgcn_mfma_f32_16x16x32_bf16(a0, bfrag[0][2], acc2, 0, 0, 0);
        acc2 = __builtin_amdgcn_mfma_f32_16x16x32_bf16(a1, bfrag[1][2], acc2, 0, 0, 0);
        acc3 = __builtin_amdgcn_mfma_f32_16x16x32_bf16(a0, bfrag[0][3], acc3, 0, 0, 0);
        acc3 = __builtin_amdgcn_mfma_f32_16x16x32_bf16(a1, bfrag[1][3], acc3, 0, 0, 0);
        #pragma unroll
        for (int r = 0; r < 4; ++r) {
            int m = quad * 4 + r;
            int g = __shfl(out_idx, m);
            if (base + m < pend) {
                float* dst = out + (size_t)g * C_DIM + col;
                unsafeAtomicAdd(dst +  0, acc0[r]);
                unsafeAtomicAdd(dst + 16, acc1[r]);
                unsafeAtomicAdd(dst + 32, acc2[r]);
                unsafeAtomicAdd(dst + 48, acc3[r]);
            }
        }
    }
}

__global__ __launch_bounds__(256)
void k2_stats(const float* __restrict__ acc, float* __restrict__ sums, int n_rows)
{
    int tid = threadIdx.x;
    int ch  = tid & 63;
    int sub = tid >> 6;
    float s = 0.f, s2 = 0.f;
    for (int r = blockIdx.x * 4 + sub; r < n_rows; r += gridDim.x * 4) {
        float v = acc[(size_t)r * C_DIM + ch];
        s  += v;
        s2 += v * v;
    }
    __shared__ float red[256];
    red[tid] = s;
    __syncthreads();
    if (tid < 64) {
        float t = red[tid] + red[tid + 64] + red[tid + 128] + red[tid + 192];
        atomicAdd(&sums[ch], t);
    }
    __syncthreads();
    red[tid] = s2;
    __syncthreads();
    if (tid < 64) {
        float t = red[tid] + red[tid + 64] + red[tid + 128] + red[tid + 192];
        atomicAdd(&sums[64 + ch], t);
    }
}

__global__ __launch_bounds__(256)
void k3_bn_relu(float* __restrict__ out, const float* __restrict__ sums,
                const float* __restrict__ gamma, const float* __restrict__ beta,
                int n_rows)
{
    int tid = blockIdx.x * 256 + threadIdx.x;
    int ch0 = (tid * 4) & 63;
    float inv_n = 1.0f / (float)n_rows;
    float sc[4], sh[4];
    #pragma unroll
    for (int j = 0; j < 4; ++j) {
        int ch    = ch0 + j;
        float m   = sums[ch] * inv_n;
        float var = sums[64 + ch] * inv_n - m * m;
        float inv = rsqrtf(var + 1e-5f);
        float g   = gamma[ch] * inv;
        sc[j] = g;
        sh[j] = beta[ch] - m * g;
    }
    size_t total = (size_t)n_rows * C_DIM / 4;
    for (size_t i = tid; i < total; i += (size_t)gridDim.x * 256) {
        float4 v = ((const float4*)out)[i];
        v.x = fmaxf(v.x * sc[0] + sh[0], 0.f);
        v.y = fmaxf(v.y * sc[1] + sh[1], 0.f);
        v.z = fmaxf(v.z * sc[2] + sh[2], 0.f);
        v.w = fmaxf(v.w * sc[3] + sh[3], 0.f);
        ((float4*)out)[i] = v;
    }
}

// ============================================================================
extern "C" void kernel_launch(void* const* d_in, const int* in_sizes, int n_in,
                              void* d_out, int out_size, void* d_ws, size_t ws_size,
                              hipStream_t stream)
{
    const float* features  = (const float*)d_in[0];
    const float* weight    = (const float*)d_in[1];
    // d_in[2] = bias (cancels in training-mode BN)
    const float* gamma     = (const float*)d_in[3];
    const float* beta      = (const float*)d_in[4];
    const int*   pairs_in  = (const int*)d_in[5];
    const int*   pairs_out = (const int*)d_in[6];

    const int n_out     = out_size / C_DIM;
    const int n_in_rows = in_sizes[0] / C_DIM;
    const int K3        = in_sizes[1] / (C_DIM * C_DIM);
    const int P         = in_sizes[5] / K3;

    float* out = (float*)d_out;

    // ws layout: sums[128f](512B) | pad | acc fp16 @1024 | fb bf16
    const size_t off_acc = 1024;
    size_t acc_bytes = (size_t)n_out * C_DIM * 2;
    size_t off_fb    = (off_acc + acc_bytes + 255) & ~(size_t)255;
    size_t fb_bytes  = (size_t)n_in_rows * C_DIM * 2;
    size_t need_b    = off_acc + acc_bytes;
    size_t need_a    = off_fb + fb_bytes;

    float*  sums   = (float*)d_ws;
    __half* acc    = (__half*)((char*)d_ws + off_acc);
    bf16_t* fbf16  = (bf16_t*)((char*)d_ws + off_fb);

    const int rows_per_block = 512;
    dim3 g1((P + rows_per_block - 1) / rows_per_block, K3);

    if (ws_size >= need_a) {
        // ---- 4-dispatch primary path ----
        k_prep<<<dim3(2048), 256, 0, stream>>>(features, fbf16,
                                               (float4*)acc, (float*)d_ws,
                                               n_in_rows * 16,
                                               (int)(acc_bytes / 16));

        k1_fp16<<<g1, 256, 0, stream>>>(features, fbf16, weight, pairs_in,
                                        pairs_out, acc, P, rows_per_block, 1);

        k2_stats_h<<<dim3(512), 256, 0, stream>>>(acc, sums, n_out);
        k3_bn_relu_h<<<dim3(1024), 256, 0, stream>>>(acc, out, sums, gamma,
                                                     beta, n_out);
    } else if (ws_size >= need_b) {
        // ---- R6 path without bf16 table (f32 feature loads) ----
        hipMemsetAsync(d_ws, 0, off_acc + acc_bytes, stream);
        k1_fp16<<<g1, 256, 0, stream>>>(features, fbf16, weight, pairs_in,
                                        pairs_out, acc, P, rows_per_block, 0);
        k2_stats_h<<<dim3(512), 256, 0, stream>>>(acc, sums, n_out);
        k3_bn_relu_h<<<dim3(1024), 256, 0, stream>>>(acc, out, sums, gamma,
                                                     beta, n_out);
    } else {
        // ---- R1 fp32 path ----
        hipMemsetAsync(d_out, 0, (size_t)out_size * sizeof(float), stream);
        hipMemsetAsync(d_ws, 0, 512, stream);

        k1_scatter_gemm<<<g1, 256, 0, stream>>>(features, weight, pairs_in,
                                                pairs_out, out, P, rows_per_block);
        k2_stats<<<dim3(1024), 256, 0, stream>>>(out, sums, n_out);
        k3_bn_relu<<<dim3(1024), 256, 0, stream>>>(out, sums, gamma, beta, n_out);
    }
}